// Round 17
// baseline (45.530 us; speedup 1.0000x reference)
//
#include <hip/hip_runtime.h>
#include <hip/hip_bf16.h>
#include <stdint.h>

#define N 8192
#define D 256
#define RB4 128                        // fp4 row = 128 bytes
#define ROWB 256                       // rows per simlse block (8 waves x 32)
#define COLG 16                        // column groups
#define COLS_PER_BLK (N / COLG)        // 512
#define CTILE 32                       // cols per tile
#define NT (COLS_PER_BLK / CTILE)      // 16 tiles -> 8 pairs
#define TILE_BYTES (CTILE * RB4)       // 4096 B
#define E_CONST 2.71828182845904523536f
#define QSCALE 19.2179587f             // 16 * sqrt(log2 e)

typedef __attribute__((ext_vector_type(4))) int i32x4;
typedef __attribute__((ext_vector_type(8))) int i32x8;
typedef __attribute__((ext_vector_type(16))) float f32x16;

typedef const __attribute__((address_space(1))) void gvoid_t;
typedef __attribute__((address_space(3))) void lvoid_t;
__device__ inline void gload_lds16(const void* g, void* l) {
  __builtin_amdgcn_global_load_lds((gvoid_t*)g, (lvoid_t*)l, 16, 0, 0);
}

// fp32 -> fp4 e2m1 code (0,.5,1,1.5,2,3,4,6), input pre-scaled by QSCALE
__device__ inline unsigned enc4(float x) {
  unsigned s = (__float_as_uint(x) >> 31) << 3;
  float m = fabsf(x) * QSCALE;
  unsigned c;
  if (m < 1.75f) c = (m < 0.75f) ? (m < 0.25f ? 0u : 1u) : (m < 1.25f ? 2u : 3u);
  else           c = (m < 3.5f)  ? (m < 2.5f ? 4u : 5u)  : (m < 5.0f ? 6u : 7u);
  return s | c;
}

// ---- kernel 1: normalize fp32->fp4 + positive-pair dot + out zero-init ----
// Block b: rows {2b, 2b+1, 2b+4096, 2b+4097}; pos[i]=pos[i+4096]=dot pair.
__global__ __launch_bounds__(256) void norm_kernel(const float* __restrict__ feat,
                                                   unsigned char* __restrict__ f4,
                                                   float* __restrict__ pos,
                                                   float* __restrict__ out) {
  __shared__ float4 sh[4][64];
  int wave = threadIdx.x >> 6, lane = threadIdx.x & 63;
  int base = blockIdx.x << 1;
  int row = (wave < 2) ? (base + wave) : (4096 + base + (wave - 2));
  const float4 v = *(const float4*)(feat + (size_t)row * D + lane * 4);
  float ss = v.x * v.x + v.y * v.y + v.z * v.z + v.w * v.w;
  for (int m = 1; m < 64; m <<= 1) ss += __shfl_xor(ss, m, 64);
  float rn = 1.0f / fmaxf(sqrtf(ss), 1e-12f);
  float4 nv = make_float4(v.x * rn, v.y * rn, v.z * rn, v.w * rn);
  // pack 4 nibbles: elem 2j -> low nibble of byte j
  unsigned short pk = (unsigned short)(enc4(nv.x) | (enc4(nv.y) << 4) |
                                       (enc4(nv.z) << 8) | (enc4(nv.w) << 12));
  *(unsigned short*)(f4 + (size_t)row * RB4 + lane * 2) = pk;
  sh[wave][lane] = nv;
  __syncthreads();
  if (wave < 2) {
    float4 q = sh[wave + 2][lane];
    float d = nv.x * q.x + nv.y * q.y + nv.z * q.z + nv.w * q.w;
    for (int m = 1; m < 64; m <<= 1) d += __shfl_xor(d, m, 64);
    if (lane == 0) {
      pos[base + wave] = d;
      pos[4096 + base + wave] = d;
    }
  }
  if (blockIdx.x == 0 && threadIdx.x == 0) out[0] = 0.0f;
}

// ---- kernel 2: fp4 sim + sum(exp(sim)); slab output ----
// R16 structure with fp4 operands: 32x32x64 f8f6f4 MFMA fmt=4, scale 2^-4
// per side (log2e folded into quantization -> bare exp2 in the loop).
// Pair schedule: one vmcnt(0)+barrier per 2 tiles, post-barrier pair staging,
// 4-tile 16 KB LDS ring, both-sides XOR swizzle (8 slots per 128-B row).
__global__ __launch_bounds__(512, 4) void simlse_kernel(const unsigned char* __restrict__ f4,
                                                        float* __restrict__ slab) {
  __shared__ char lds[4 * TILE_BYTES];   // 16 KB
  const char* fb = (const char*)f4;
  int tid = threadIdx.x;
  int wave = tid >> 6, lane = tid & 63;
  int c31 = lane & 31, h = lane >> 5;
  int rb = blockIdx.x >> 4;   // 0..31
  int cg = blockIdx.x & 15;   // 0..15
  int rowbase = rb * ROWB + wave * 32;

  // A fragments: lane holds row (rowbase+c31); per m: 16 B at h*16 + m*32
  // (32 fp4 nibbles covering k = m*64 + h*32 .. +31). Data in regs 0-3.
  i32x8 a[4];
  {
    const char* ar = fb + (size_t)(rowbase + c31) * RB4 + h * 16;
    const i32x4 z4 = {0, 0, 0, 0};
#pragma unroll
    for (int m = 0; m < 4; ++m) {
      i32x4 lo = *(const i32x4*)(ar + m * 32);
      a[m] = __builtin_shufflevector(lo, z4, 0, 1, 2, 3, 4, 5, 6, 7);
    }
  }
#pragma unroll
  for (int m = 0; m < 4; ++m)
    asm volatile("" : "+v"(a[m]));   // pin: forbid rematerialization / sinking

  float srow[16];
#pragma unroll
  for (int r = 0; r < 16; ++r) srow[r] = 0.0f;

  // staging: 512 threads x 16 B = one 8 KB PAIR of tiles per pass
  int colbase = cg * COLS_PER_BLK;
  int o0 = tid * 16;                              // 0..8191
  int pr = o0 >> 7;                               // pair col-row 0..63
  int g0 = (o0 & 127) ^ ((pr & 7) << 4);          // pre-swizzled source byte
  const i32x4 z4 = {0, 0, 0, 0};

#define STAGEPAIR(uu)                                                          \
  {                                                                            \
    char* stg = lds + ((uu) & 1) * 8192;                                       \
    size_t cb = (size_t)(colbase + (uu) * 2 * CTILE);                          \
    gload_lds16(fb + (cb + pr) * RB4 + g0, stg + wave * 1024);                 \
  }

#define COMPUTE(tt)                                                            \
  {                                                                            \
    const char* bb = lds + ((tt) & 3) * TILE_BYTES + c31 * RB4;                \
    f32x16 acc = {0, 0, 0, 0, 0, 0, 0, 0, 0, 0, 0, 0, 0, 0, 0, 0};            \
    _Pragma("unroll")                                                          \
    for (int m = 0; m < 4; ++m) {                                              \
      int s = m * 2 + h;                                                       \
      i32x4 lo = *(const i32x4*)(bb + ((s ^ (c31 & 7)) << 4));                 \
      i32x8 bv = __builtin_shufflevector(lo, z4, 0, 1, 2, 3, 4, 5, 6, 7);      \
      acc = __builtin_amdgcn_mfma_scale_f32_32x32x64_f8f6f4(                   \
          a[m], bv, acc, 4, 4, 0, 123, 0, 123);                                \
    }                                                                          \
    _Pragma("unroll")                                                          \
    for (int r = 0; r < 16; ++r) srow[r] += __builtin_amdgcn_exp2f(acc[r]);    \
  }

  STAGEPAIR(0);

  const int NP = NT / 2;   // 8 pairs
  for (int u = 0; u < NP; ++u) {
    asm volatile("s_waitcnt vmcnt(0)" ::: "memory");   // pair u's tiles landed
    __builtin_amdgcn_sched_barrier(0);
    __builtin_amdgcn_s_barrier();
    __builtin_amdgcn_sched_barrier(0);
    if (u + 1 < NP) STAGEPAIR(u + 1);   // post-barrier: other half of ring free
    COMPUTE(2 * u);
    COMPUTE(2 * u + 1);
  }
#undef STAGEPAIR
#undef COMPUTE

  // reduce each row-sum across the 32 lanes (cols) sharing h
#pragma unroll
  for (int r = 0; r < 16; ++r) {
    srow[r] += __shfl_xor(srow[r], 1, 64);
    srow[r] += __shfl_xor(srow[r], 2, 64);
    srow[r] += __shfl_xor(srow[r], 4, 64);
    srow[r] += __shfl_xor(srow[r], 8, 64);
    srow[r] += __shfl_xor(srow[r], 16, 64);
  }
  if (c31 == 0) {
#pragma unroll
    for (int r = 0; r < 16; ++r) {
      int grow = rowbase + (r & 3) + 8 * (r >> 2) + 4 * h;   // C/D row mapping
      slab[(size_t)cg * N + grow] = srow[r];
    }
  }
}

// ---- kernel 3: combine slab -> scalar loss ----
__global__ __launch_bounds__(256) void final_kernel(const float* __restrict__ slab,
                                                    const float* __restrict__ pos,
                                                    float* __restrict__ out) {
  int tid = threadIdx.x;
  int row = blockIdx.x * 256 + tid;
  float ssum = 0.0f;
#pragma unroll
  for (int c = 0; c < COLG; ++c) ssum += slab[(size_t)c * N + row];
  float v = __logf(ssum - E_CONST) - pos[row];   // remove diag exp(sim_ii) ~= e
  for (int m = 1; m < 64; m <<= 1) v += __shfl_xor(v, m, 64);
  __shared__ float r4[4];
  if ((tid & 63) == 0) r4[tid >> 6] = v;
  __syncthreads();
  if (tid == 0)
    atomicAdd(out, (r4[0] + r4[1] + r4[2] + r4[3]) * (1.0f / (float)N));
}

extern "C" void kernel_launch(void* const* d_in, const int* in_sizes, int n_in,
                              void* d_out, int out_size, void* d_ws, size_t ws_size,
                              hipStream_t stream) {
  const float* feat = (const float*)d_in[0];
  unsigned char* f4 = (unsigned char*)d_ws;                                    // 1 MB
  float* pos  = (float*)((char*)d_ws + (size_t)N * RB4);                       // 32 KB
  float* slab = (float*)((char*)d_ws + (size_t)N * RB4 + (size_t)N * 4);       // 512 KB
  float* out = (float*)d_out;

  norm_kernel<<<N / 4, 256, 0, stream>>>(feat, f4, pos, out);
  simlse_kernel<<<(N / ROWB) * COLG, 512, 0, stream>>>(f4, slab);
  final_kernel<<<N / 256, 256, 0, stream>>>(slab, pos, out);
}

// Round 18
// 33.048 us; speedup vs baseline: 1.3777x; 1.3777x over previous
//
#include <hip/hip_runtime.h>
#include <hip/hip_bf16.h>
#include <stdint.h>

#define N 8192
#define D 256                          // fp8 row = 256 bytes
#define ROWB 256                       // rows per simlse block (8 waves x 32)
#define COLG 16                        // column groups
#define COLS_PER_BLK (N / COLG)        // 512
#define CTILE 32                       // cols per tile
#define NT (COLS_PER_BLK / CTILE)      // 16 tiles -> 8 pairs
#define TILE_BYTES (CTILE * D)         // 8192 B
#define NBUF 4                         // 32 KB LDS ring
#define E_CONST 2.71828182845904523536f

typedef __attribute__((ext_vector_type(4))) int i32x4;
typedef __attribute__((ext_vector_type(8))) int i32x8;
typedef __attribute__((ext_vector_type(16))) float f32x16;

typedef const __attribute__((address_space(1))) void gvoid_t;
typedef __attribute__((address_space(3))) void lvoid_t;
__device__ inline void gload_lds16(const void* g, void* l) {
  __builtin_amdgcn_global_load_lds((gvoid_t*)g, (lvoid_t*)l, 16, 0, 0);
}

// fp32 -> e4m3fn (RNE), manual fallback if builtin missing
#if !__has_builtin(__builtin_amdgcn_cvt_pk_fp8_f32)
__device__ inline unsigned int f2e4m3(float x) {
  union { float f; unsigned u; } c; c.f = x;
  unsigned s = (c.u >> 31) << 7;
  float ax = fabsf(x);
  if (!(ax > 0.0f)) return s;
  if (ax >= 448.0f) return s | 0x7E;
  int e; float m = frexpf(ax, &e);
  int E = e - 1 + 7;
  if (E <= 0) {
    int qi = (int)rintf(ax * 512.0f);
    if (qi > 7) return s | 0x08;
    return s | (unsigned)qi;
  }
  int qi = (int)rintf(m * 16.0f);
  if (qi == 16) { qi = 8; E += 1; }
  if (E > 15) return s | 0x7E;
  return s | (unsigned)((E << 3) | (qi - 8));
}
#endif

// ---- kernel 1: normalize fp32->fp8 + positive-pair dot + out zero-init ----
// Block b: rows {2b, 2b+1, 2b+4096, 2b+4097}; pos[i]=pos[i+4096]=dot pair.
__global__ __launch_bounds__(256) void norm_kernel(const float* __restrict__ feat,
                                                   unsigned char* __restrict__ f8,
                                                   float* __restrict__ pos,
                                                   float* __restrict__ out) {
  __shared__ float4 sh[4][64];
  int wave = threadIdx.x >> 6, lane = threadIdx.x & 63;
  int base = blockIdx.x << 1;
  int row = (wave < 2) ? (base + wave) : (4096 + base + (wave - 2));
  const float4 v = *(const float4*)(feat + (size_t)row * D + lane * 4);
  float ss = v.x * v.x + v.y * v.y + v.z * v.z + v.w * v.w;
  for (int m = 1; m < 64; m <<= 1) ss += __shfl_xor(ss, m, 64);
  float rn = 1.0f / fmaxf(sqrtf(ss), 1e-12f);
  float4 nv = make_float4(v.x * rn, v.y * rn, v.z * rn, v.w * rn);
#if __has_builtin(__builtin_amdgcn_cvt_pk_fp8_f32)
  int p = __builtin_amdgcn_cvt_pk_fp8_f32(nv.x, nv.y, 0, 0);
  p = __builtin_amdgcn_cvt_pk_fp8_f32(nv.z, nv.w, p, 1);
#else
  int p = (int)(f2e4m3(nv.x) | (f2e4m3(nv.y) << 8) |
                (f2e4m3(nv.z) << 16) | (f2e4m3(nv.w) << 24));
#endif
  *(int*)(f8 + (size_t)row * D + lane * 4) = p;
  sh[wave][lane] = nv;
  __syncthreads();
  if (wave < 2) {
    float4 q = sh[wave + 2][lane];
    float d = nv.x * q.x + nv.y * q.y + nv.z * q.z + nv.w * q.w;
    for (int m = 1; m < 64; m <<= 1) d += __shfl_xor(d, m, 64);
    if (lane == 0) {
      pos[base + wave] = d;
      pos[4096 + base + wave] = d;
    }
  }
  if (blockIdx.x == 0 && threadIdx.x == 0) out[0] = 0.0f;
}

// ---- kernel 2: fused fp8 sim + partial sum(exp(sim)); slab output ----
// Proven best (R16, 33.2 us total): 32x32x64 MX MFMA (scale=1.0), 8 waves x
// 32 rows (ROWB=256), pair schedule: one vmcnt(0)+barrier per 2 tiles,
// post-barrier staging, 4-deep 32 KB LDS ring, both-sides XOR swizzle,
// single-pass tile staging (512 thr x 16 B = 8 KB).
__global__ __launch_bounds__(512, 4) void simlse_kernel(const unsigned char* __restrict__ f8,
                                                        float* __restrict__ slab) {
  __shared__ char lds[NBUF * TILE_BYTES];   // 32 KB
  const char* fb = (const char*)f8;
  int tid = threadIdx.x;
  int wave = tid >> 6, lane = tid & 63;
  int c31 = lane & 31, h = lane >> 5;
  int rb = blockIdx.x >> 4;   // 0..31
  int cg = blockIdx.x & 15;   // 0..15
  int rowbase = rb * ROWB + wave * 32;

  // A fragments: lane holds row (rowbase + c31), k-bytes m*64 + h*32 .. +31
  i32x8 a[4];
  {
    const char* ar = fb + (size_t)(rowbase + c31) * D + h * 32;
#pragma unroll
    for (int m = 0; m < 4; ++m) {
      i32x4 lo = *(const i32x4*)(ar + m * 64);
      i32x4 hi = *(const i32x4*)(ar + m * 64 + 16);
      a[m] = __builtin_shufflevector(lo, hi, 0, 1, 2, 3, 4, 5, 6, 7);
    }
  }
#pragma unroll
  for (int m = 0; m < 4; ++m)
    asm volatile("" : "+v"(a[m]));   // pin: forbid rematerialization / sinking

  float srow[16];
#pragma unroll
  for (int r = 0; r < 16; ++r) srow[r] = 0.0f;

  // staging: 512 threads x 16 B = one 8 KB tile in a single pass
  int colbase = cg * COLS_PER_BLK;
  int o0 = tid * 16;                              // 0..8191
  int r0 = o0 >> 8;                               // tile row 0..31
  int g0 = (o0 & 255) ^ ((r0 & 7) << 4);          // pre-swizzled source byte
  int sw = (c31 & 7) << 4;                        // read-side swizzle

#define STAGE(tt)                                                              \
  {                                                                            \
    char* stg = lds + ((tt) & (NBUF - 1)) * TILE_BYTES;                        \
    size_t cb = (size_t)(colbase + (tt) * CTILE);                              \
    gload_lds16(fb + (cb + r0) * D + g0, stg + wave * 1024);                   \
  }

#define COMPUTE(tt)                                                            \
  {                                                                            \
    const char* bb = lds + ((tt) & (NBUF - 1)) * TILE_BYTES + c31 * 256;       \
    f32x16 acc = {0, 0, 0, 0, 0, 0, 0, 0, 0, 0, 0, 0, 0, 0, 0, 0};            \
    _Pragma("unroll")                                                          \
    for (int m = 0; m < 4; ++m) {                                              \
      int base = m * 64 + h * 32;                                              \
      i32x4 lo = *(const i32x4*)(bb + (base ^ sw));                            \
      i32x4 hi = *(const i32x4*)(bb + ((base + 16) ^ sw));                     \
      i32x8 bv = __builtin_shufflevector(lo, hi, 0, 1, 2, 3, 4, 5, 6, 7);      \
      acc = __builtin_amdgcn_mfma_scale_f32_32x32x64_f8f6f4(                   \
          a[m], bv, acc, 0, 0, 0, 127, 0, 127);                                \
    }                                                                          \
    _Pragma("unroll")                                                          \
    for (int r = 0; r < 16; ++r) srow[r] += __expf(acc[r]);                    \
  }

  STAGE(0);
  STAGE(1);

  const int NP = NT / 2;   // 8 pairs
  for (int u = 0; u < NP; ++u) {
    asm volatile("s_waitcnt vmcnt(0)" ::: "memory");   // this pair's tiles landed
    __builtin_amdgcn_sched_barrier(0);
    __builtin_amdgcn_s_barrier();
    __builtin_amdgcn_sched_barrier(0);
    if (u + 1 < NP) {       // post-barrier staging: prev pair's buffers free
      STAGE(2 * u + 2);
      STAGE(2 * u + 3);
    }
    COMPUTE(2 * u);
    COMPUTE(2 * u + 1);
  }
#undef STAGE
#undef COMPUTE

  // reduce each row-sum across the 32 lanes (cols) sharing h
#pragma unroll
  for (int r = 0; r < 16; ++r) {
    srow[r] += __shfl_xor(srow[r], 1, 64);
    srow[r] += __shfl_xor(srow[r], 2, 64);
    srow[r] += __shfl_xor(srow[r], 4, 64);
    srow[r] += __shfl_xor(srow[r], 8, 64);
    srow[r] += __shfl_xor(srow[r], 16, 64);
  }
  if (c31 == 0) {
#pragma unroll
    for (int r = 0; r < 16; ++r) {
      int grow = rowbase + (r & 3) + 8 * (r >> 2) + 4 * h;   // C/D row mapping
      slab[(size_t)cg * N + grow] = srow[r];
    }
  }
}

// ---- kernel 3: combine slab -> scalar loss ----
__global__ __launch_bounds__(256) void final_kernel(const float* __restrict__ slab,
                                                    const float* __restrict__ pos,
                                                    float* __restrict__ out) {
  int tid = threadIdx.x;
  int row = blockIdx.x * 256 + tid;
  float ssum = 0.0f;
#pragma unroll
  for (int c = 0; c < COLG; ++c) ssum += slab[(size_t)c * N + row];
  float v = __logf(ssum - E_CONST) - pos[row];   // remove diag exp(sim_ii) ~= e
  for (int m = 1; m < 64; m <<= 1) v += __shfl_xor(v, m, 64);
  __shared__ float r4[4];
  if ((tid & 63) == 0) r4[tid >> 6] = v;
  __syncthreads();
  if (tid == 0)
    atomicAdd(out, (r4[0] + r4[1] + r4[2] + r4[3]) * (1.0f / (float)N));
}

extern "C" void kernel_launch(void* const* d_in, const int* in_sizes, int n_in,
                              void* d_out, int out_size, void* d_ws, size_t ws_size,
                              hipStream_t stream) {
  const float* feat = (const float*)d_in[0];
  unsigned char* f8 = (unsigned char*)d_ws;                                    // 2 MB
  float* pos  = (float*)((char*)d_ws + (size_t)N * D);                         // 32 KB
  float* slab = (float*)((char*)d_ws + (size_t)N * D + (size_t)N * 4);         // 512 KB
  float* out = (float*)d_out;

  norm_kernel<<<N / 4, 256, 0, stream>>>(feat, f8, pos, out);
  simlse_kernel<<<(N / ROWB) * COLG, 512, 0, stream>>>(f8, slab);
  final_kernel<<<N / 256, 256, 0, stream>>>(slab, pos, out);
}

// Round 19
// 32.849 us; speedup vs baseline: 1.3861x; 1.0061x over previous
//
#include <hip/hip_runtime.h>
#include <hip/hip_bf16.h>
#include <stdint.h>

#define N 8192
#define D 256
#define PLANE ((size_t)(N * 32 + 1024))   // k-chunk plane stride, padded vs set-aliasing
#define ROWB 128                          // rows per simlse block (4 waves x 32)
#define COLG 16                           // column groups
#define COLS_PER_BLK (N / COLG)           // 512
#define NT (COLS_PER_BLK / 32)            // 16 col-tiles
#define E_CONST 2.71828182845904523536f

typedef __attribute__((ext_vector_type(4))) int i32x4;
typedef __attribute__((ext_vector_type(8))) int i32x8;
typedef __attribute__((ext_vector_type(16))) float f32x16;

// fp32 -> e4m3fn (RNE), manual fallback if builtin missing
#if !__has_builtin(__builtin_amdgcn_cvt_pk_fp8_f32)
__device__ inline unsigned int f2e4m3(float x) {
  union { float f; unsigned u; } c; c.f = x;
  unsigned s = (c.u >> 31) << 7;
  float ax = fabsf(x);
  if (!(ax > 0.0f)) return s;
  if (ax >= 448.0f) return s | 0x7E;
  int e; float m = frexpf(ax, &e);
  int E = e - 1 + 7;
  if (E <= 0) {
    int qi = (int)rintf(ax * 512.0f);
    if (qi > 7) return s | 0x08;
    return s | (unsigned)qi;
  }
  int qi = (int)rintf(m * 16.0f);
  if (qi == 16) { qi = 8; E += 1; }
  if (E > 15) return s | 0x7E;
  return s | (unsigned)((E << 3) | (qi - 8));
}
#endif

// ---- kernel 1: normalize fp32 -> fp8, stored K-CHUNK-MAJOR + pos + zero out ----
// f8t layout: plane kc (=byte_chunk k/32, 0..7), within plane: row*32 + (k%32).
// Block b: rows {2b, 2b+1, 2b+4096, 2b+4097}; pos[i]=pos[i+4096]=dot pair.
__global__ __launch_bounds__(256) void norm_kernel(const float* __restrict__ feat,
                                                   unsigned char* __restrict__ f8t,
                                                   float* __restrict__ pos,
                                                   float* __restrict__ out) {
  __shared__ float4 sh[4][64];
  int wave = threadIdx.x >> 6, lane = threadIdx.x & 63;
  int base = blockIdx.x << 1;
  int row = (wave < 2) ? (base + wave) : (4096 + base + (wave - 2));
  const float4 v = *(const float4*)(feat + (size_t)row * D + lane * 4);
  float ss = v.x * v.x + v.y * v.y + v.z * v.z + v.w * v.w;
  for (int m = 1; m < 64; m <<= 1) ss += __shfl_xor(ss, m, 64);
  float rn = 1.0f / fmaxf(sqrtf(ss), 1e-12f);
  float4 nv = make_float4(v.x * rn, v.y * rn, v.z * rn, v.w * rn);
#if __has_builtin(__builtin_amdgcn_cvt_pk_fp8_f32)
  int p = __builtin_amdgcn_cvt_pk_fp8_f32(nv.x, nv.y, 0, 0);
  p = __builtin_amdgcn_cvt_pk_fp8_f32(nv.z, nv.w, p, 1);
#else
  int p = (int)(f2e4m3(nv.x) | (f2e4m3(nv.y) << 8) |
                (f2e4m3(nv.z) << 16) | (f2e4m3(nv.w) << 24));
#endif
  // byte index in row = lane*4 .. +3  ->  chunk lane>>3, offset (lane&7)*4
  *(int*)(f8t + (size_t)(lane >> 3) * PLANE + (size_t)row * 32 + (lane & 7) * 4) = p;
  sh[wave][lane] = nv;
  __syncthreads();
  if (wave < 2) {
    float4 q = sh[wave + 2][lane];
    float d = nv.x * q.x + nv.y * q.y + nv.z * q.z + nv.w * q.w;
    for (int m = 1; m < 64; m <<= 1) d += __shfl_xor(d, m, 64);
    if (lane == 0) {
      pos[base + wave] = d;
      pos[4096 + base + wave] = d;
    }
  }
  if (blockIdx.x == 0 && threadIdx.x == 0) out[0] = 0.0f;
}

// ---- kernel 2: fp8 sim + sum(exp(sim)); NO LDS, NO BARRIERS ----
// B-fragments loaded straight from L1/L2-resident f8t (coalesced via the
// chunk-major layout); each wave free-runs its 16 tiles; compiler pipelines.
__global__ __launch_bounds__(256, 4) void simlse_kernel(const unsigned char* __restrict__ f8t,
                                                        float* __restrict__ slab) {
  const char* fb = (const char*)f8t;
  int tid = threadIdx.x;
  int wave = tid >> 6, lane = tid & 63;
  int c31 = lane & 31, h = lane >> 5;
  int rb = blockIdx.x >> 4;   // 0..63
  int cg = blockIdx.x & 15;   // 0..15
  int rowbase = rb * ROWB + wave * 32;
  int colbase = cg * COLS_PER_BLK;

  // A fragments: lane = row (rowbase+c31); per m the 32 B of chunk 2m+h
  i32x8 a[4];
#pragma unroll
  for (int m = 0; m < 4; ++m) {
    size_t ba = (size_t)(2 * m + h) * PLANE + (size_t)(rowbase + c31) * 32;
    i32x4 lo = *(const i32x4*)(fb + ba);
    i32x4 hi = *(const i32x4*)(fb + ba + 16);
    a[m] = __builtin_shufflevector(lo, hi, 0, 1, 2, 3, 4, 5, 6, 7);
  }
#pragma unroll
  for (int m = 0; m < 4; ++m)
    asm volatile("" : "+v"(a[m]));   // pin: forbid rematerialization / sinking

  float srow[16];
#pragma unroll
  for (int r = 0; r < 16; ++r) srow[r] = 0.0f;

#pragma unroll 2
  for (int t = 0; t < NT; ++t) {
    size_t cb32 = (size_t)(colbase + t * 32 + c31) * 32;
    f32x16 acc = {0, 0, 0, 0, 0, 0, 0, 0, 0, 0, 0, 0, 0, 0, 0, 0};
#pragma unroll
    for (int m = 0; m < 4; ++m) {
      size_t ba = (size_t)(2 * m + h) * PLANE + cb32;
      i32x4 lo = *(const i32x4*)(fb + ba);
      i32x4 hi = *(const i32x4*)(fb + ba + 16);
      i32x8 bv = __builtin_shufflevector(lo, hi, 0, 1, 2, 3, 4, 5, 6, 7);
      acc = __builtin_amdgcn_mfma_scale_f32_32x32x64_f8f6f4(
          a[m], bv, acc, 0, 0, 0, 127, 0, 127);
    }
#pragma unroll
    for (int r = 0; r < 16; ++r) srow[r] += __expf(acc[r]);
  }

  // reduce each row-sum across the 32 lanes (cols) sharing h
#pragma unroll
  for (int r = 0; r < 16; ++r) {
    srow[r] += __shfl_xor(srow[r], 1, 64);
    srow[r] += __shfl_xor(srow[r], 2, 64);
    srow[r] += __shfl_xor(srow[r], 4, 64);
    srow[r] += __shfl_xor(srow[r], 8, 64);
    srow[r] += __shfl_xor(srow[r], 16, 64);
  }
  if (c31 == 0) {
#pragma unroll
    for (int r = 0; r < 16; ++r) {
      int grow = rowbase + (r & 3) + 8 * (r >> 2) + 4 * h;   // C/D row mapping
      slab[(size_t)cg * N + grow] = srow[r];
    }
  }
}

// ---- kernel 3: combine slab -> scalar loss ----
__global__ __launch_bounds__(256) void final_kernel(const float* __restrict__ slab,
                                                    const float* __restrict__ pos,
                                                    float* __restrict__ out) {
  int tid = threadIdx.x;
  int row = blockIdx.x * 256 + tid;
  float ssum = 0.0f;
#pragma unroll
  for (int c = 0; c < COLG; ++c) ssum += slab[(size_t)c * N + row];
  float v = __logf(ssum - E_CONST) - pos[row];   // remove diag exp(sim_ii) ~= e
  for (int m = 1; m < 64; m <<= 1) v += __shfl_xor(v, m, 64);
  __shared__ float r4[4];
  if ((tid & 63) == 0) r4[tid >> 6] = v;
  __syncthreads();
  if (tid == 0)
    atomicAdd(out, (r4[0] + r4[1] + r4[2] + r4[3]) * (1.0f / (float)N));
}

extern "C" void kernel_launch(void* const* d_in, const int* in_sizes, int n_in,
                              void* d_out, int out_size, void* d_ws, size_t ws_size,
                              hipStream_t stream) {
  const float* feat = (const float*)d_in[0];
  unsigned char* f8t = (unsigned char*)d_ws;                                   // ~2.01 MB
  float* pos  = (float*)((char*)d_ws + 8 * PLANE);                             // 32 KB
  float* slab = (float*)((char*)d_ws + 8 * PLANE + (size_t)N * 4);             // 512 KB
  float* out = (float*)d_out;

  norm_kernel<<<N / 4, 256, 0, stream>>>(feat, f8t, pos, out);
  simlse_kernel<<<(N / ROWB) * COLG, 256, 0, stream>>>(f8t, slab);
  final_kernel<<<N / 256, 256, 0, stream>>>(slab, pos, out);
}